// Round 6
// baseline (1671.860 us; speedup 1.0000x reference)
//
#include <hip/hip_runtime.h>
#include <hip/hip_fp16.h>

// GRU_23613730193671 on MI355X (gfx950) — round 6: compile fix + split polls
// B=256 T=256 D=128 H=512; out = fc2(relu(fc1(relu(hT_layer1))))
//
// Round-5 failed to compile: "+v" tied ext-vector asm operands unsupported.
// Round-6:
//  - wait_pulls = bare `s_waitcnt vmcnt(0)` asm ("memory" clobber). Pulled
//    values are consumed ONLY by LDS stores, which cannot cross a volatile
//    memory-clobber asm -> ordering is safe without operand ties.
//  - x prefetch = plain C++ float4 loads (compiler-managed waitcnt).
//  - split polls at F: poll f0 (set back at D) -> issue h0 pulls -> poll f1
//    -> issue h1 pulls. h0 pull RT now overlaps h1 publish ack + flag prop.
// Everything else = round 4 structure (PASS @ 1313 us).

#define B_  256
#define T_  256
#define D_  128
#define H_  512
#define G3  1536
#define BH  (B_ * H_)

typedef _Float16 h8  __attribute__((ext_vector_type(8)));
typedef _Float16 h2v __attribute__((ext_vector_type(2)));
typedef float    f4  __attribute__((ext_vector_type(4)));

#define MFMA16(a, b, c) __builtin_amdgcn_mfma_f32_16x16x32_f16((a), (b), (c), 0, 0, 0)

__device__ __forceinline__ int swz(int c, int r) { return (c & ~7) | ((c + r) & 7); }

__device__ __forceinline__ float sigmoid_f(float v) { return 1.f / (1.f + __expf(-v)); }
__device__ __forceinline__ float tanh_f(float v) {
    float ex = __expf(2.f * v);
    return 1.f - 2.f / (ex + 1.f);
}

// ---- issue 4 coherent 16B loads, NO waitcnt (drained at phase A) ----
__device__ __forceinline__ void ld4_issue(
    const _Float16* p0, const _Float16* p1, const _Float16* p2, const _Float16* p3,
    h8& r0, h8& r1, h8& r2, h8& r3) {
    asm volatile(
        "global_load_dwordx4 %0, %4, off sc0 sc1\n\t"
        "global_load_dwordx4 %1, %5, off sc0 sc1\n\t"
        "global_load_dwordx4 %2, %6, off sc0 sc1\n\t"
        "global_load_dwordx4 %3, %7, off sc0 sc1"
        : "=&v"(r0), "=&v"(r1), "=&v"(r2), "=&v"(r3)
        : "v"(p0), "v"(p1), "v"(p2), "v"(p3)
        : "memory");
}
// coherent 16B store (fire-and-forget; drained by explicit vmcnt)
__device__ __forceinline__ void st16_sc(_Float16* p, h8 v) {
    asm volatile("global_store_dwordx4 %0, %1, off sc0 sc1" :: "v"(p), "v"(v) : "memory");
}

// ---------------------------------------------------------------------------
__global__ void convert_weights(const float* __restrict__ Wih0,
                                const float* __restrict__ Whh0,
                                const float* __restrict__ Wih1,
                                const float* __restrict__ Whh1,
                                _Float16* __restrict__ Wcat0,
                                _Float16* __restrict__ Wcat1) {
    int g = blockIdx.x;  // 0..1535 (gate-row)
    for (int k = threadIdx.x; k < D_; k += blockDim.x)
        Wcat0[(size_t)g * 640 + k] = (_Float16)Wih0[(size_t)g * D_ + k];
    for (int k = threadIdx.x; k < H_; k += blockDim.x) {
        Wcat0[(size_t)g * 640 + 128 + k]  = (_Float16)Whh0[(size_t)g * H_ + k];
        Wcat1[(size_t)g * 1024 + k]       = (_Float16)Wih1[(size_t)g * H_ + k];
        Wcat1[(size_t)g * 1024 + 512 + k] = (_Float16)Whh1[(size_t)g * H_ + k];
    }
}

// ---------------------------------------------------------------------------
// Phases per step u (0..256):
//  A: s_waitcnt vmcnt(0); stage x(u) (plain loads) + pulled h0(u-1)/h1(u-2); sync
//  B: L0(u) MFMA -> ghp/anx; sync
//  C: L0 epi -> h0(u) staged into As x-region; sync
//  D: wave0: publish h0(u) (store+ack+f0=u+1) || all: L1(u-1) MFMA; sync
//  E: L1 epi -> h1(u-1) in-place (+hT at u==256); sync
//  F: wave0 publish h1(u-1)+f1=u; poll f0 -> issue h0 pulls -> poll f1 ->
//     issue h1 pulls + x(u+1) loads; NO barrier (A's LDS writes are gated by
//     the flags: any wave past the poll implies own wave0 finished its LDS
//     gathers), loop to A.
__global__ __launch_bounds__(256, 1) void gru_fused(
    const float* __restrict__ x,
    const _Float16* __restrict__ Wcat0, const _Float16* __restrict__ Wcat1,
    const float* __restrict__ bih0, const float* __restrict__ bhh0,
    const float* __restrict__ bih1, const float* __restrict__ bhh1,
    _Float16* __restrict__ h0ring,   // [2][B][H]
    _Float16* __restrict__ h1ring,   // [2][B][H]
    float* __restrict__ hT,          // [B][H]
    int* __restrict__ flag0base,     // [16 bg][16 cg]
    int* __restrict__ flag1base) {   // [16 bg][16 cg]
    __shared__ __attribute__((aligned(16))) _Float16 As[16 * 1152];
    __shared__ float ghp[4][16][100];
    __shared__ float anx[16][32];

    const int tid  = threadIdx.x;
    const int bg   = blockIdx.x & 15;
    const int cg   = blockIdx.x >> 4;
    const int wave = tid >> 6;
    const int lane = tid & 63;
    const int l15  = lane & 15;
    const int q    = lane >> 4;
    const int b0   = bg * 16;
    const int hc0  = cg * 32;
    int* f0g = flag0base + bg * 16;
    int* f1g = flag1base + bg * 16;

    // ---- W fragments in registers (B-operand: col n = l15, k = q*8+j) ----
    h8 wf0[5][6];
#pragma unroll
    for (int s = 0; s < 5; ++s) {
        const int kh = (wave * 5 + s) * 32 + q * 8;
#pragma unroll
        for (int nt = 0; nt < 6; ++nt) {
            const int grow = (nt >> 1) * H_ + hc0 + (nt & 1) * 16 + l15;
            wf0[s][nt] = *(const h8*)(Wcat0 + (size_t)grow * 640 + kh);
        }
    }
    h8 wf1[8][6];
#pragma unroll
    for (int s = 0; s < 8; ++s) {
        const int kh = (wave * 8 + s) * 32 + q * 8;
#pragma unroll
        for (int nt = 0; nt < 6; ++nt) {
            const int grow = (nt >> 1) * H_ + hc0 + (nt & 1) * 16 + l15;
            wf1[s][nt] = *(const h8*)(Wcat1 + (size_t)grow * 1024 + kh);
        }
    }
    // ---- biases ----
    float br0[2], bz0[2], bi0[2], bh0[2], br1[2], bz1[2], bi1[2], bh1[2];
    {
        const int jj = (tid & 15) * 2;
#pragma unroll
        for (int e = 0; e < 2; ++e) {
            const int col = hc0 + jj + e;
            br0[e] = bih0[col] + bhh0[col];
            bz0[e] = bih0[H_ + col] + bhh0[H_ + col];
            bi0[e] = bih0[2 * H_ + col];
            bh0[e] = bhh0[2 * H_ + col];
            br1[e] = bih1[col] + bhh1[col];
            bz1[e] = bih1[H_ + col] + bhh1[H_ + col];
            bi1[e] = bih1[2 * H_ + col];
            bh1[e] = bhh1[2 * H_ + col];
        }
    }

    const int r   = tid >> 4;      // staging row
    const int c16 = tid & 15;      // staging chunk lane

    // pulled data (live across F -> A)
    h8 p0 = {}, p1 = {}, p2 = {}, p3 = {};     // h0
    h8 q0 = {}, q1 = {}, q2 = {}, q3 = {};     // h1
    float4 vx0 = {0,0,0,0}, vx1 = {0,0,0,0};   // x row halves

    // preamble: x(0) loads (plain; compiler-managed wait)
    {
        const float* xp = x + ((size_t)(b0 + r) * T_ + 0) * D_ + c16 * 8;
        vx0 = *(const float4*)(xp);
        vx1 = *(const float4*)(xp + 4);
    }

#pragma unroll 1
    for (int u = 0; u <= T_; ++u) {
        // ================= A: drain pulls, stage =================
        asm volatile("s_waitcnt vmcnt(0)" ::: "memory");
        if (u < T_) {
            h8 hx;
            hx[0] = (_Float16)vx0.x; hx[1] = (_Float16)vx0.y;
            hx[2] = (_Float16)vx0.z; hx[3] = (_Float16)vx0.w;
            hx[4] = (_Float16)vx1.x; hx[5] = (_Float16)vx1.y;
            hx[6] = (_Float16)vx1.z; hx[7] = (_Float16)vx1.w;
            *(h8*)&As[r * 1152 + swz(c16, r) * 8] = hx;
        }
        *(h8*)&As[r * 1152 + swz(16 + c16,      r) * 8] = p0;
        *(h8*)&As[r * 1152 + swz(16 + c16 + 16, r) * 8] = p1;
        *(h8*)&As[r * 1152 + swz(16 + c16 + 32, r) * 8] = p2;
        *(h8*)&As[r * 1152 + swz(16 + c16 + 48, r) * 8] = p3;
        *(h8*)&As[r * 1152 + swz(80 + c16,      r) * 8] = q0;
        *(h8*)&As[r * 1152 + swz(80 + c16 + 16, r) * 8] = q1;
        *(h8*)&As[r * 1152 + swz(80 + c16 + 32, r) * 8] = q2;
        *(h8*)&As[r * 1152 + swz(80 + c16 + 48, r) * 8] = q3;
        __syncthreads();
        // ================= B: L0 MFMA =================
        if (u < T_) {
            f4 arz0 = {0,0,0,0}, arz1 = {0,0,0,0}, arz2 = {0,0,0,0}, arz3 = {0,0,0,0};
            f4 anx0 = {0,0,0,0}, anx1 = {0,0,0,0}, anh0 = {0,0,0,0}, anh1 = {0,0,0,0};
#pragma unroll
            for (int s = 0; s < 5; ++s) {
                const int kstep = wave * 5 + s;
                const int c = kstep * 4 + q;
                h8 a = *(const h8*)&As[l15 * 1152 + swz(c, l15) * 8];
                arz0 = MFMA16(a, wf0[s][0], arz0);
                arz1 = MFMA16(a, wf0[s][1], arz1);
                arz2 = MFMA16(a, wf0[s][2], arz2);
                arz3 = MFMA16(a, wf0[s][3], arz3);
                if (kstep < 4) {
                    anx0 = MFMA16(a, wf0[s][4], anx0);
                    anx1 = MFMA16(a, wf0[s][5], anx1);
                } else {
                    anh0 = MFMA16(a, wf0[s][4], anh0);
                    anh1 = MFMA16(a, wf0[s][5], anh1);
                }
            }
#pragma unroll
            for (int i = 0; i < 4; ++i) {
                float* row = &ghp[wave][q * 4 + i][0];
                row[ 0 + l15] = arz0[i];
                row[16 + l15] = arz1[i];
                row[32 + l15] = arz2[i];
                row[48 + l15] = arz3[i];
                row[64 + l15] = anh0[i];
                row[80 + l15] = anh1[i];
            }
            if (wave == 0) {
#pragma unroll
                for (int i = 0; i < 4; ++i) {
                    anx[q * 4 + i][l15]      = anx0[i];
                    anx[q * 4 + i][16 + l15] = anx1[i];
                }
            }
        }
        __syncthreads();
        // ================= C: L0 epi -> h0(u) into x-region =================
        if (u < T_) {
            const int er = r;
            const int jj = c16 * 2;
            h2v out2;
#pragma unroll
            for (int e = 0; e < 2; ++e) {
                const int j = jj + e;
                float gr = 0.f, gz = 0.f, ghn = 0.f;
#pragma unroll
                for (int w = 0; w < 4; ++w) {
                    gr  += ghp[w][er][j];
                    gz  += ghp[w][er][32 + j];
                    ghn += ghp[w][er][64 + j];
                }
                const float gxn = anx[er][j];
                const float rr = sigmoid_f(gr + br0[e]);
                const float zz = sigmoid_f(gz + bz0[e]);
                const float nn = tanh_f(gxn + bi0[e] + rr * (ghn + bh0[e]));
                const int hcol = hc0 + j;
                const float hp = (float)As[er * 1152 + swz(16 + (hcol >> 3), er) * 8 + (hcol & 7)];
                out2[e] = (_Float16)((1.f - zz) * nn + zz * hp);
            }
            *(h2v*)&As[er * 1152 + swz(jj >> 3, er) * 8 + (jj & 7)] = out2;
        }
        __syncthreads();
        // ========== D: wave0 publish h0 (+f0) || L1 MFMA ==========
        if (wave == 0 && u < T_) {
            const int row = lane >> 2, ch = lane & 3;
            h8 v = *(const h8*)&As[row * 1152 + swz(ch, row) * 8];
            st16_sc(h0ring + (size_t)(u & 1) * BH + (size_t)(b0 + row) * H_ + hc0 + ch * 8, v);
            asm volatile("s_waitcnt vmcnt(0)" ::: "memory");
            if (lane == 0)
                __hip_atomic_store(f0g + cg, u + 1, __ATOMIC_RELAXED, __HIP_MEMORY_SCOPE_AGENT);
        }
        if (u > 0) {
            f4 arz0 = {0,0,0,0}, arz1 = {0,0,0,0}, arz2 = {0,0,0,0}, arz3 = {0,0,0,0};
            f4 an0 = {0,0,0,0}, an1 = {0,0,0,0};
#pragma unroll
            for (int s = 0; s < 8; ++s) {
                const int c = 16 + (wave * 8 + s) * 4 + q;
                h8 a = *(const h8*)&As[l15 * 1152 + swz(c, l15) * 8];
                arz0 = MFMA16(a, wf1[s][0], arz0);
                arz1 = MFMA16(a, wf1[s][1], arz1);
                arz2 = MFMA16(a, wf1[s][2], arz2);
                arz3 = MFMA16(a, wf1[s][3], arz3);
                an0  = MFMA16(a, wf1[s][4], an0);
                an1  = MFMA16(a, wf1[s][5], an1);
            }
#pragma unroll
            for (int i = 0; i < 4; ++i) {
                float* row = &ghp[wave][q * 4 + i][0];
                row[ 0 + l15] = arz0[i];
                row[16 + l15] = arz1[i];
                row[32 + l15] = arz2[i];
                row[48 + l15] = arz3[i];
                row[64 + l15] = an0[i];
                row[80 + l15] = an1[i];
            }
        }
        __syncthreads();
        // ================= E: L1 epi -> h1(u-1) in place =================
        if (u > 0) {
            const int er = r;
            const int jj = c16 * 2;
            h2v out2;
            float hvf[2];
#pragma unroll
            for (int e = 0; e < 2; ++e) {
                const int j = jj + e;
                float gr = 0.f, gz = 0.f;
#pragma unroll
                for (int w = 0; w < 4; ++w) {
                    gr += ghp[w][er][j];
                    gz += ghp[w][er][32 + j];
                }
                const float gxn = ghp[0][er][64 + j] + ghp[1][er][64 + j];
                const float ghn = ghp[2][er][64 + j] + ghp[3][er][64 + j];
                const float rr = sigmoid_f(gr + br1[e]);
                const float zz = sigmoid_f(gz + bz1[e]);
                const float nn = tanh_f(gxn + bi1[e] + rr * (ghn + bh1[e]));
                const int hcol = hc0 + j;
                const float hp = (float)As[er * 1152 + swz(80 + (hcol >> 3), er) * 8 + (hcol & 7)];
                hvf[e] = (1.f - zz) * nn + zz * hp;
                out2[e] = (_Float16)hvf[e];
            }
            const int hcol0 = hc0 + jj;
            *(h2v*)&As[er * 1152 + swz(80 + (hcol0 >> 3), er) * 8 + (hcol0 & 7)] = out2;
            if (u == T_) {
                hT[(size_t)(b0 + er) * H_ + hc0 + jj]     = hvf[0];
                hT[(size_t)(b0 + er) * H_ + hc0 + jj + 1] = hvf[1];
            }
        }
        __syncthreads();
        // ===== F: publish h1; split polls; issue pulls =====
        if (u < T_) {
            if (wave == 0 && u > 0) {
                const int row = lane >> 2, ch = lane & 3;
                const int gch = 80 + (hc0 >> 3) + ch;
                h8 v = *(const h8*)&As[row * 1152 + swz(gch, row) * 8];
                st16_sc(h1ring + (size_t)((u + 1) & 1) * BH + (size_t)(b0 + row) * H_ + hc0 + ch * 8, v);
                asm volatile("s_waitcnt vmcnt(0)" ::: "memory");
                if (lane == 0)
                    __hip_atomic_store(f1g + cg, u, __ATOMIC_RELAXED, __HIP_MEMORY_SCOPE_AGENT);
            }
            // poll f0 >= u+1 (set at D, usually already visible)
            {
                int fv;
                do {
                    fv = (lane < 16) ? __hip_atomic_load(f0g + lane, __ATOMIC_RELAXED, __HIP_MEMORY_SCOPE_AGENT)
                                     : 0x7fffffff;
                    if (__all(fv >= u + 1)) break;
                    __builtin_amdgcn_s_sleep(1);
                } while (true);
            }
            // issue h0 pulls (overlaps h1 publish ack + f1 propagation)
            {
                const _Float16* h0p = h0ring + (size_t)(u & 1) * BH + (size_t)(b0 + r) * H_;
                ld4_issue(h0p + c16 * 8, h0p + (c16 + 16) * 8,
                          h0p + (c16 + 32) * 8, h0p + (c16 + 48) * 8,
                          p0, p1, p2, p3);
            }
            // poll f1 >= u
            {
                int fv;
                do {
                    fv = (lane < 16) ? __hip_atomic_load(f1g + lane, __ATOMIC_RELAXED, __HIP_MEMORY_SCOPE_AGENT)
                                     : 0x7fffffff;
                    if (__all(fv >= u)) break;
                    __builtin_amdgcn_s_sleep(1);
                } while (true);
            }
            // issue h1 pulls + x(u+1) prefetch
            {
                const _Float16* h1p = h1ring + (size_t)((u + 1) & 1) * BH + (size_t)(b0 + r) * H_;
                ld4_issue(h1p + c16 * 8, h1p + (c16 + 16) * 8,
                          h1p + (c16 + 32) * 8, h1p + (c16 + 48) * 8,
                          q0, q1, q2, q3);
                if (u + 1 < T_) {
                    const float* xp = x + ((size_t)(b0 + r) * T_ + (u + 1)) * D_ + c16 * 8;
                    vx0 = *(const float4*)(xp);
                    vx1 = *(const float4*)(xp + 4);
                }
            }
            // no barrier: any wave past the polls implies own wave0 finished
            // its LDS gathers (flags are set only after them), so A's LDS
            // writes cannot race with F's reads.
        }
    }
}

// ---------------------------------------------------------------------------
__global__ __launch_bounds__(128) void head_kernel(
    const float* __restrict__ hT, const float* __restrict__ fc1_w,
    const float* __restrict__ fc1_b, const float* __restrict__ fc2_w,
    const float* __restrict__ fc2_b, float* __restrict__ out) {
    __shared__ float hs[512];
    __shared__ float a1[128];
    const int b = blockIdx.x, tid = threadIdx.x;
    for (int k = tid; k < H_; k += 128) {
        float v = hT[(size_t)b * H_ + k];
        hs[k] = v > 0.f ? v : 0.f;
    }
    __syncthreads();
    float acc = fc1_b[tid];
    const float* wr = fc1_w + (size_t)tid * H_;
    for (int k = 0; k < H_; k += 4) {
        float4 w = *(const float4*)(wr + k);
        acc += w.x * hs[k] + w.y * hs[k + 1] + w.z * hs[k + 2] + w.w * hs[k + 3];
    }
    a1[tid] = acc > 0.f ? acc : 0.f;
    __syncthreads();
    if (tid < 10) {
        float o = fc2_b[tid];
        const float* w2 = fc2_w + (size_t)tid * 128;
        for (int k = 0; k < 128; ++k) o += w2[k] * a1[k];
        out[(size_t)b * 10 + tid] = o;
    }
}

// ---------------------------------------------------------------------------
extern "C" void kernel_launch(void* const* d_in, const int* in_sizes, int n_in,
                              void* d_out, int out_size, void* d_ws, size_t ws_size,
                              hipStream_t stream) {
    const float* x    = (const float*)d_in[0];
    const float* Wih0 = (const float*)d_in[1];
    const float* Whh0 = (const float*)d_in[2];
    const float* bih0 = (const float*)d_in[3];
    const float* bhh0 = (const float*)d_in[4];
    const float* Wih1 = (const float*)d_in[5];
    const float* Whh1 = (const float*)d_in[6];
    const float* bih1 = (const float*)d_in[7];
    const float* bhh1 = (const float*)d_in[8];
    const float* fc1w = (const float*)d_in[9];
    const float* fc1b = (const float*)d_in[10];
    const float* fc2w = (const float*)d_in[11];
    const float* fc2b = (const float*)d_in[12];

    char* ws = (char*)d_ws;
    size_t off = 0;
    int* flags0 = (int*)(ws + off); off += 16 * 16 * 4;        // 1 KB
    int* flags1 = (int*)(ws + off); off += 16 * 16 * 4;        // 1 KB
    off = (off + 255) & ~(size_t)255;
    _Float16* Wcat0 = (_Float16*)(ws + off); off += (size_t)G3 * 640 * 2;   // 1.97 MB
    off = (off + 255) & ~(size_t)255;
    _Float16* Wcat1 = (_Float16*)(ws + off); off += (size_t)G3 * 1024 * 2;  // 3.15 MB
    off = (off + 255) & ~(size_t)255;
    _Float16* h0ring = (_Float16*)(ws + off); off += (size_t)2 * BH * 2;    // 0.5 MB
    _Float16* h1ring = (_Float16*)(ws + off); off += (size_t)2 * BH * 2;    // 0.5 MB
    float* hT = (float*)(ws + off); off += (size_t)BH * 4;                  // 0.5 MB
    // total ~6.7 MB

    (void)hipMemsetAsync(flags0, 0, 2 * 16 * 16 * 4, stream);        // zero flags
    (void)hipMemsetAsync(h1ring, 0, (size_t)2 * BH * 2, stream);     // h1(-1) = 0

    hipLaunchKernelGGL(convert_weights, dim3(G3), dim3(256), 0, stream,
                       Wih0, Whh0, Wih1, Whh1, Wcat0, Wcat1);
    hipLaunchKernelGGL(gru_fused, dim3(256), dim3(256), 0, stream,
                       x, Wcat0, Wcat1, bih0, bhh0, bih1, bhh1,
                       h0ring, h1ring, hT, flags0, flags1);
    hipLaunchKernelGGL(head_kernel, dim3(B_), dim3(128), 0, stream,
                       hT, fc1w, fc1b, fc2w, fc2b, (float*)d_out);
}

// Round 7
// 1285.485 us; speedup vs baseline: 1.3006x; 1.3006x over previous
//
#include <hip/hip_runtime.h>
#include <hip/hip_fp16.h>

// GRU_23613730193671 on MI355X (gfx950) — round 7: LAG-2 software pipeline
// B=256 T=256 D=128 H=512; out = fc2(relu(fc1(relu(hT_layer1))))
//
// r4 (1313us): 3 serialized MALL RTs/step. r6 (1672us): all-wave polls added
// 2 poll-RTs to every wave's path (lesson: a poll = 1 sc-load RT even when
// the flag is set).
//
// r7 structure: L1 runs 2 steps behind L0 and FIRST in each iter:
//   iter u (0..257):  L1 at t1=u-2, then L0 at t0=u.
// Phases: P1 stage(x,h1)+spec-f0 | P2 L1-MFMA | P3 eval-f0,pull-h0,epi1+
// publish-h1,stage-h0 | P5 f1-flag,L0-MFMA,spec-f1 | P5b epi0+publish-h0,
// eval-f1,pull-h1,x-prefetch | P6 f0-flag.
//  - every publish->consume edge has >= half-iter slack
//  - spec flag checks: sc-load issued a phase early, evaluated after compute
//    (fast path ~0.2us), poll fallback (slow path)
//  - epilogue threads sc-store h directly to rings (no wave0 gathers);
//    per-wave vmcnt(0) acks; flag set after following barrier
//  - 3-deep rings (WAR margin); counting-free vmcnt(0) everywhere

#define B_  256
#define T_  256
#define D_  128
#define H_  512
#define G3  1536
#define BH  (B_ * H_)

typedef _Float16 h8  __attribute__((ext_vector_type(8)));
typedef _Float16 h2v __attribute__((ext_vector_type(2)));
typedef float    f4  __attribute__((ext_vector_type(4)));

#define MFMA16(a, b, c) __builtin_amdgcn_mfma_f32_16x16x32_f16((a), (b), (c), 0, 0, 0)

__device__ __forceinline__ int swz(int c, int r) { return (c & ~7) | ((c + r) & 7); }

__device__ __forceinline__ float sigmoid_f(float v) { return 1.f / (1.f + __expf(-v)); }
__device__ __forceinline__ float tanh_f(float v) {
    float ex = __expf(2.f * v);
    return 1.f - 2.f / (ex + 1.f);
}

// ---- asm transport helpers (all volatile + memory clobber => ordered) ----
__device__ __forceinline__ void vm0() {
    asm volatile("s_waitcnt vmcnt(0)" ::: "memory");
}
__device__ __forceinline__ void ld4_sc_issue(
    const _Float16* p0, const _Float16* p1, const _Float16* p2, const _Float16* p3,
    h8& r0, h8& r1, h8& r2, h8& r3) {
    asm volatile(
        "global_load_dwordx4 %0, %4, off sc0 sc1\n\t"
        "global_load_dwordx4 %1, %5, off sc0 sc1\n\t"
        "global_load_dwordx4 %2, %6, off sc0 sc1\n\t"
        "global_load_dwordx4 %3, %7, off sc0 sc1"
        : "=&v"(r0), "=&v"(r1), "=&v"(r2), "=&v"(r3)
        : "v"(p0), "v"(p1), "v"(p2), "v"(p3)
        : "memory");
}
__device__ __forceinline__ void ldx2_issue(const float* p, float4& a, float4& b) {
    asm volatile(
        "global_load_dwordx4 %0, %2, off\n\t"
        "global_load_dwordx4 %1, %3, off"
        : "=&v"(a), "=&v"(b)
        : "v"(p), "v"(p + 4)
        : "memory");
}
__device__ __forceinline__ void chk_issue(const int* p, int& r) {
    asm volatile("global_load_dword %0, %1, off sc0 sc1" : "=v"(r) : "v"(p) : "memory");
}
__device__ __forceinline__ void st4_sc(_Float16* p, h2v v) {
    union { h2v h; unsigned int u; } cv; cv.h = v;
    asm volatile("global_store_dword %0, %1, off sc0 sc1" :: "v"(p), "v"(cv.u) : "memory");
}

// slow-path poll (rare)
__device__ __forceinline__ void poll_flags(const int* fg, int lane, int tgt) {
    int fv;
    do {
        fv = __hip_atomic_load(fg + (lane & 15), __ATOMIC_RELAXED, __HIP_MEMORY_SCOPE_AGENT);
        if (__all(fv >= tgt)) break;
        __builtin_amdgcn_s_sleep(1);
    } while (true);
}

// ---------------------------------------------------------------------------
__global__ void convert_weights(const float* __restrict__ Wih0,
                                const float* __restrict__ Whh0,
                                const float* __restrict__ Wih1,
                                const float* __restrict__ Whh1,
                                _Float16* __restrict__ Wcat0,
                                _Float16* __restrict__ Wcat1) {
    int g = blockIdx.x;  // 0..1535 (gate-row)
    for (int k = threadIdx.x; k < D_; k += blockDim.x)
        Wcat0[(size_t)g * 640 + k] = (_Float16)Wih0[(size_t)g * D_ + k];
    for (int k = threadIdx.x; k < H_; k += blockDim.x) {
        Wcat0[(size_t)g * 640 + 128 + k]  = (_Float16)Whh0[(size_t)g * H_ + k];
        Wcat1[(size_t)g * 1024 + k]       = (_Float16)Wih1[(size_t)g * H_ + k];
        Wcat1[(size_t)g * 1024 + 512 + k] = (_Float16)Whh1[(size_t)g * H_ + k];
    }
}

// ---------------------------------------------------------------------------
// Flag semantics: f0 = s  <=>  h0(s-1) published (set at P6 of iter s-1)
//                 f1 = s  <=>  h1(s-1) published (set at P5-top of iter s+1)
// Ring slots: h(t) -> ring[t % 3].
__global__ __launch_bounds__(256, 1) void gru_fused(
    const float* __restrict__ x,
    const _Float16* __restrict__ Wcat0, const _Float16* __restrict__ Wcat1,
    const float* __restrict__ bih0, const float* __restrict__ bhh0,
    const float* __restrict__ bih1, const float* __restrict__ bhh1,
    _Float16* __restrict__ h0ring,   // [3][B][H]
    _Float16* __restrict__ h1ring,   // [3][B][H]
    float* __restrict__ hT,          // [B][H]
    int* __restrict__ flag0base,     // [16 bg][16 cg]
    int* __restrict__ flag1base) {   // [16 bg][16 cg]
    __shared__ __attribute__((aligned(16))) _Float16 As[16 * 1152];
    __shared__ float ghp[4][16][100];
    __shared__ float anx[16][32];

    const int tid  = threadIdx.x;
    const int bg   = blockIdx.x & 15;
    const int cg   = blockIdx.x >> 4;
    const int wave = tid >> 6;
    const int lane = tid & 63;
    const int l15  = lane & 15;
    const int q    = lane >> 4;
    const int b0   = bg * 16;
    const int hc0  = cg * 32;
    int* f0g = flag0base + bg * 16;
    int* f1g = flag1base + bg * 16;

    // ---- W fragments in registers (B-operand: col n = l15, k = q*8+j) ----
    h8 wf0[5][6];
#pragma unroll
    for (int s = 0; s < 5; ++s) {
        const int kh = (wave * 5 + s) * 32 + q * 8;
#pragma unroll
        for (int nt = 0; nt < 6; ++nt) {
            const int grow = (nt >> 1) * H_ + hc0 + (nt & 1) * 16 + l15;
            wf0[s][nt] = *(const h8*)(Wcat0 + (size_t)grow * 640 + kh);
        }
    }
    h8 wf1[8][6];
#pragma unroll
    for (int s = 0; s < 8; ++s) {
        const int kh = (wave * 8 + s) * 32 + q * 8;
#pragma unroll
        for (int nt = 0; nt < 6; ++nt) {
            const int grow = (nt >> 1) * H_ + hc0 + (nt & 1) * 16 + l15;
            wf1[s][nt] = *(const h8*)(Wcat1 + (size_t)grow * 1024 + kh);
        }
    }
    // ---- biases ----
    float br0[2], bz0[2], bi0[2], bh0[2], br1[2], bz1[2], bi1[2], bh1[2];
    {
        const int jj = (tid & 15) * 2;
#pragma unroll
        for (int e = 0; e < 2; ++e) {
            const int col = hc0 + jj + e;
            br0[e] = bih0[col] + bhh0[col];
            bz0[e] = bih0[H_ + col] + bhh0[H_ + col];
            bi0[e] = bih0[2 * H_ + col];
            bh0[e] = bhh0[2 * H_ + col];
            br1[e] = bih1[col] + bhh1[col];
            bz1[e] = bih1[H_ + col] + bhh1[H_ + col];
            bi1[e] = bih1[2 * H_ + col];
            bh1[e] = bhh1[2 * H_ + col];
        }
    }

    const int r   = tid >> 4;      // staging row / epi row
    const int c16 = tid & 15;      // staging chunk lane
    const int jj  = c16 * 2;       // epi col pair

    // persistent pulled data
    h8 p0 = {}, p1 = {}, p2 = {}, p3 = {};     // h0 pulls
    h8 q0 = {}, q1 = {}, q2 = {}, q3 = {};     // h1 pulls
    float4 vx0 = {0,0,0,0}, vx1 = {0,0,0,0};   // x(u) halves
    int rf0 = 0, rf1 = 0;                      // spec flag-check regs

    // preamble: issue x(0)
    ldx2_issue(x + ((size_t)(b0 + r) * T_ + 0) * D_ + c16 * 8, vx0, vx1);

#pragma unroll 1
    for (int u = 0; u <= T_ + 1; ++u) {
        // ===== P1: drain pulls; stage X(x(u)) + H1(h1(u-3)); spec f0 =====
        vm0();
        if (u < T_) {
            h8 hx;
            hx[0] = (_Float16)vx0.x; hx[1] = (_Float16)vx0.y;
            hx[2] = (_Float16)vx0.z; hx[3] = (_Float16)vx0.w;
            hx[4] = (_Float16)vx1.x; hx[5] = (_Float16)vx1.y;
            hx[6] = (_Float16)vx1.z; hx[7] = (_Float16)vx1.w;
            *(h8*)&As[r * 1152 + swz(c16, r) * 8] = hx;
        }
        *(h8*)&As[r * 1152 + swz(80 + c16,      r) * 8] = q0;
        *(h8*)&As[r * 1152 + swz(80 + c16 + 16, r) * 8] = q1;
        *(h8*)&As[r * 1152 + swz(80 + c16 + 32, r) * 8] = q2;
        *(h8*)&As[r * 1152 + swz(80 + c16 + 48, r) * 8] = q3;
        if (u >= 1 && u <= T_) chk_issue(f0g + l15, rf0);   // eval at P3
        __syncthreads();
        // ===== P2: L1 MFMA (t1 = u-2): K = H0(h0(u-2)) | H1(h1(u-3)) =====
        if (u >= 2) {
            f4 arz0 = {0,0,0,0}, arz1 = {0,0,0,0}, arz2 = {0,0,0,0}, arz3 = {0,0,0,0};
            f4 an0 = {0,0,0,0}, an1 = {0,0,0,0};
#pragma unroll
            for (int s = 0; s < 8; ++s) {
                const int c = 16 + (wave * 8 + s) * 4 + q;
                h8 a = *(const h8*)&As[l15 * 1152 + swz(c, l15) * 8];
                arz0 = MFMA16(a, wf1[s][0], arz0);
                arz1 = MFMA16(a, wf1[s][1], arz1);
                arz2 = MFMA16(a, wf1[s][2], arz2);
                arz3 = MFMA16(a, wf1[s][3], arz3);
                an0  = MFMA16(a, wf1[s][4], an0);
                an1  = MFMA16(a, wf1[s][5], an1);
            }
#pragma unroll
            for (int i = 0; i < 4; ++i) {
                float* row = &ghp[wave][q * 4 + i][0];
                row[ 0 + l15] = arz0[i];
                row[16 + l15] = arz1[i];
                row[32 + l15] = arz2[i];
                row[48 + l15] = arz3[i];
                row[64 + l15] = an0[i];
                row[80 + l15] = an1[i];
            }
        }
        __syncthreads();
        // ===== P3: eval f0 -> pull h0(u-1); epi1 -> publish h1(u-2);
        //           stage H0 =====
        vm0();   // drains rf0 (residual only; issued back at P1)
        if (u >= 1 && u <= T_) {
            if (!__all(rf0 >= u)) poll_flags(f0g, lane, u);
            const _Float16* h0p = h0ring + (size_t)((u - 1) % 3) * BH + (size_t)(b0 + r) * H_;
            ld4_sc_issue(h0p + c16 * 8, h0p + (c16 + 16) * 8,
                         h0p + (c16 + 32) * 8, h0p + (c16 + 48) * 8,
                         p0, p1, p2, p3);
        }
        if (u >= 2) {   // epi1 for t1 = u-2 (pulls fly during the VALU work)
            h2v out2;
            float hvf[2];
#pragma unroll
            for (int e = 0; e < 2; ++e) {
                const int j = jj + e;
                float gr = 0.f, gz = 0.f;
#pragma unroll
                for (int w = 0; w < 4; ++w) {
                    gr += ghp[w][r][j];
                    gz += ghp[w][r][32 + j];
                }
                const float gxn = ghp[0][r][64 + j] + ghp[1][r][64 + j];
                const float ghn = ghp[2][r][64 + j] + ghp[3][r][64 + j];
                const float rr = sigmoid_f(gr + br1[e]);
                const float zz = sigmoid_f(gz + bz1[e]);
                const float nn = tanh_f(gxn + bi1[e] + rr * (ghn + bh1[e]));
                const int hcol = hc0 + j;
                const float hp = (float)As[r * 1152 + swz(80 + (hcol >> 3), r) * 8 + (hcol & 7)];
                hvf[e] = (1.f - zz) * nn + zz * hp;
                out2[e] = (_Float16)hvf[e];
            }
            if (u <= T_)
                st4_sc(h1ring + (size_t)((u - 2) % 3) * BH + (size_t)(b0 + r) * H_ + hc0 + jj, out2);
            else {
                hT[(size_t)(b0 + r) * H_ + hc0 + jj]     = hvf[0];
                hT[(size_t)(b0 + r) * H_ + hc0 + jj + 1] = hvf[1];
            }
        }
        vm0();   // drains h0-pulls + epi1 store (ack before f1; pulls before stage)
        if (u <= T_) {   // stage H0 := h0(u-1) (u==T_+1 keeps h0(255) for L1)
            *(h8*)&As[r * 1152 + swz(16 + c16,      r) * 8] = p0;
            *(h8*)&As[r * 1152 + swz(16 + c16 + 16, r) * 8] = p1;
            *(h8*)&As[r * 1152 + swz(16 + c16 + 32, r) * 8] = p2;
            *(h8*)&As[r * 1152 + swz(16 + c16 + 48, r) * 8] = p3;
        }
        __syncthreads();
        if (u <= T_) {
            // ===== P5: f1 flag; L0 MFMA (t0 = u); spec f1 =====
            if (tid == 0 && u >= 2)
                __hip_atomic_store(f1g + cg, u - 1, __ATOMIC_RELAXED, __HIP_MEMORY_SCOPE_AGENT);
            if (u < T_) {
                f4 arz0 = {0,0,0,0}, arz1 = {0,0,0,0}, arz2 = {0,0,0,0}, arz3 = {0,0,0,0};
                f4 anx0 = {0,0,0,0}, anx1 = {0,0,0,0}, anh0 = {0,0,0,0}, anh1 = {0,0,0,0};
#pragma unroll
                for (int s = 0; s < 5; ++s) {
                    const int kstep = wave * 5 + s;
                    const int c = kstep * 4 + q;
                    h8 a = *(const h8*)&As[l15 * 1152 + swz(c, l15) * 8];
                    arz0 = MFMA16(a, wf0[s][0], arz0);
                    arz1 = MFMA16(a, wf0[s][1], arz1);
                    arz2 = MFMA16(a, wf0[s][2], arz2);
                    arz3 = MFMA16(a, wf0[s][3], arz3);
                    if (kstep < 4) {
                        anx0 = MFMA16(a, wf0[s][4], anx0);
                        anx1 = MFMA16(a, wf0[s][5], anx1);
                    } else {
                        anh0 = MFMA16(a, wf0[s][4], anh0);
                        anh1 = MFMA16(a, wf0[s][5], anh1);
                    }
                }
#pragma unroll
                for (int i = 0; i < 4; ++i) {
                    float* row = &ghp[wave][q * 4 + i][0];
                    row[ 0 + l15] = arz0[i];
                    row[16 + l15] = arz1[i];
                    row[32 + l15] = arz2[i];
                    row[48 + l15] = arz3[i];
                    row[64 + l15] = anh0[i];
                    row[80 + l15] = anh1[i];
                }
                if (wave == 0) {
#pragma unroll
                    for (int i = 0; i < 4; ++i) {
                        anx[q * 4 + i][l15]      = anx0[i];
                        anx[q * 4 + i][16 + l15] = anx1[i];
                    }
                }
            }
            if (u >= 2) chk_issue(f1g + l15, rf1);   // eval at P5b
            __syncthreads();
            // ===== P5b: epi0 -> publish h0(u); eval f1 -> pull h1(u-2);
            //            x(u+1) prefetch =====
            h2v out2;
            if (u < T_) {
#pragma unroll
                for (int e = 0; e < 2; ++e) {
                    const int j = jj + e;
                    float gr = 0.f, gz = 0.f, ghn = 0.f;
#pragma unroll
                    for (int w = 0; w < 4; ++w) {
                        gr  += ghp[w][r][j];
                        gz  += ghp[w][r][32 + j];
                        ghn += ghp[w][r][64 + j];
                    }
                    const float gxn = anx[r][j];
                    const float rr = sigmoid_f(gr + br0[e]);
                    const float zz = sigmoid_f(gz + bz0[e]);
                    const float nn = tanh_f(gxn + bi0[e] + rr * (ghn + bh0[e]));
                    const int hcol = hc0 + j;
                    const float hp = (float)As[r * 1152 + swz(16 + (hcol >> 3), r) * 8 + (hcol & 7)];
                    out2[e] = (_Float16)((1.f - zz) * nn + zz * hp);
                }
                st4_sc(h0ring + (size_t)(u % 3) * BH + (size_t)(b0 + r) * H_ + hc0 + jj, out2);
            }
            vm0();   // drains rf1 + epi0 store (ack before f0 at P6)
            if (u >= 2) {
                if (!__all(rf1 >= u - 1)) poll_flags(f1g, lane, u - 1);
                const _Float16* h1p = h1ring + (size_t)((u - 2) % 3) * BH + (size_t)(b0 + r) * H_;
                ld4_sc_issue(h1p + c16 * 8, h1p + (c16 + 16) * 8,
                             h1p + (c16 + 32) * 8, h1p + (c16 + 48) * 8,
                             q0, q1, q2, q3);
            }
            if (u + 1 < T_)
                ldx2_issue(x + ((size_t)(b0 + r) * T_ + (u + 1)) * D_ + c16 * 8, vx0, vx1);
            __syncthreads();
            // ===== P6: f0 flag (all epi0 stores acked per-wave + barrier) ====
            if (tid == 0 && u < T_)
                __hip_atomic_store(f0g + cg, u + 1, __ATOMIC_RELAXED, __HIP_MEMORY_SCOPE_AGENT);
            // no trailing barrier: P1(u+1) writes X/H1, whose last readers
            // (P5 MFMA / P3 epi1-hp) all precede the P5b barrier.
        }
    }
}

// ---------------------------------------------------------------------------
__global__ __launch_bounds__(128) void head_kernel(
    const float* __restrict__ hT, const float* __restrict__ fc1_w,
    const float* __restrict__ fc1_b, const float* __restrict__ fc2_w,
    const float* __restrict__ fc2_b, float* __restrict__ out) {
    __shared__ float hs[512];
    __shared__ float a1[128];
    const int b = blockIdx.x, tid = threadIdx.x;
    for (int k = tid; k < H_; k += 128) {
        float v = hT[(size_t)b * H_ + k];
        hs[k] = v > 0.f ? v : 0.f;
    }
    __syncthreads();
    float acc = fc1_b[tid];
    const float* wr = fc1_w + (size_t)tid * H_;
    for (int k = 0; k < H_; k += 4) {
        float4 w = *(const float4*)(wr + k);
        acc += w.x * hs[k] + w.y * hs[k + 1] + w.z * hs[k + 2] + w.w * hs[k + 3];
    }
    a1[tid] = acc > 0.f ? acc : 0.f;
    __syncthreads();
    if (tid < 10) {
        float o = fc2_b[tid];
        const float* w2 = fc2_w + (size_t)tid * 128;
        for (int k = 0; k < 128; ++k) o += w2[k] * a1[k];
        out[(size_t)b * 10 + tid] = o;
    }
}

// ---------------------------------------------------------------------------
extern "C" void kernel_launch(void* const* d_in, const int* in_sizes, int n_in,
                              void* d_out, int out_size, void* d_ws, size_t ws_size,
                              hipStream_t stream) {
    const float* x    = (const float*)d_in[0];
    const float* Wih0 = (const float*)d_in[1];
    const float* Whh0 = (const float*)d_in[2];
    const float* bih0 = (const float*)d_in[3];
    const float* bhh0 = (const float*)d_in[4];
    const float* Wih1 = (const float*)d_in[5];
    const float* Whh1 = (const float*)d_in[6];
    const float* bih1 = (const float*)d_in[7];
    const float* bhh1 = (const float*)d_in[8];
    const float* fc1w = (const float*)d_in[9];
    const float* fc1b = (const float*)d_in[10];
    const float* fc2w = (const float*)d_in[11];
    const float* fc2b = (const float*)d_in[12];

    char* ws = (char*)d_ws;
    size_t off = 0;
    int* flags0 = (int*)(ws + off); off += 16 * 16 * 4;        // 1 KB
    int* flags1 = (int*)(ws + off); off += 16 * 16 * 4;        // 1 KB
    off = (off + 255) & ~(size_t)255;
    _Float16* Wcat0 = (_Float16*)(ws + off); off += (size_t)G3 * 640 * 2;   // 1.97 MB
    off = (off + 255) & ~(size_t)255;
    _Float16* Wcat1 = (_Float16*)(ws + off); off += (size_t)G3 * 1024 * 2;  // 3.15 MB
    off = (off + 255) & ~(size_t)255;
    _Float16* h0ring = (_Float16*)(ws + off); off += (size_t)3 * BH * 2;    // 0.75 MB
    _Float16* h1ring = (_Float16*)(ws + off); off += (size_t)3 * BH * 2;    // 0.75 MB
    float* hT = (float*)(ws + off); off += (size_t)BH * 4;                  // 0.5 MB
    // total ~7.5 MB

    (void)hipMemsetAsync(flags0, 0, 2 * 16 * 16 * 4, stream);  // zero both flag arrays

    hipLaunchKernelGGL(convert_weights, dim3(G3), dim3(256), 0, stream,
                       Wih0, Whh0, Wih1, Whh1, Wcat0, Wcat1);
    hipLaunchKernelGGL(gru_fused, dim3(256), dim3(256), 0, stream,
                       x, Wcat0, Wcat1, bih0, bhh0, bih1, bhh1,
                       h0ring, h1ring, hT, flags0, flags1);
    hipLaunchKernelGGL(head_kernel, dim3(B_), dim3(128), 0, stream,
                       hT, fc1w, fc1b, fc2w, fc2b, (float*)d_out);
}